// Round 15
// baseline (887.731 us; speedup 1.0000x reference)
//
#include <hip/hip_runtime.h>

typedef float v4f __attribute__((ext_vector_type(4)));
typedef float v2f __attribute__((ext_vector_type(2)));
static constexpr float EPS = 1e-6f;

#define DPP_ADD(x, ctrl, rmask)                                               \
  x += __builtin_bit_cast(float, __builtin_amdgcn_update_dpp(                 \
           0, __builtin_bit_cast(int, x), ctrl, rmask, 0xf, true))

#define LVL10(ctrl, rmask, a, b, c, d, e, f, g, h, i, j)                      \
  DPP_ADD(a, ctrl, rmask); DPP_ADD(b, ctrl, rmask); DPP_ADD(c, ctrl, rmask);  \
  DPP_ADD(d, ctrl, rmask); DPP_ADD(e, ctrl, rmask); DPP_ADD(f, ctrl, rmask);  \
  DPP_ADD(g, ctrl, rmask); DPP_ADD(h, ctrl, rmask); DPP_ADD(i, ctrl, rmask);  \
  DPP_ADD(j, ctrl, rmask)
#define WAVE_RED10(a, b, c, d, e, f, g, h, i, j)                              \
  do {                                                                        \
    LVL10(0x111, 0xf, a, b, c, d, e, f, g, h, i, j);                          \
    LVL10(0x112, 0xf, a, b, c, d, e, f, g, h, i, j);                          \
    LVL10(0x114, 0xf, a, b, c, d, e, f, g, h, i, j);                          \
    LVL10(0x118, 0xf, a, b, c, d, e, f, g, h, i, j);                          \
    LVL10(0x142, 0xa, a, b, c, d, e, f, g, h, i, j);                          \
    LVL10(0x143, 0xc, a, b, c, d, e, f, g, h, i, j);                          \
  } while (0)
#define LVL5(ctrl, rmask, a, b, c, d, e)                                      \
  DPP_ADD(a, ctrl, rmask); DPP_ADD(b, ctrl, rmask); DPP_ADD(c, ctrl, rmask);  \
  DPP_ADD(d, ctrl, rmask); DPP_ADD(e, ctrl, rmask)
#define WAVE_RED5(a, b, c, d, e)                                              \
  do {                                                                        \
    LVL5(0x111, 0xf, a, b, c, d, e); LVL5(0x112, 0xf, a, b, c, d, e);         \
    LVL5(0x114, 0xf, a, b, c, d, e); LVL5(0x118, 0xf, a, b, c, d, e);         \
    LVL5(0x142, 0xa, a, b, c, d, e); LVL5(0x143, 0xc, a, b, c, d, e);         \
  } while (0)
#define LVL4(ctrl, rmask, a, b, c, d)                                         \
  DPP_ADD(a, ctrl, rmask); DPP_ADD(b, ctrl, rmask); DPP_ADD(c, ctrl, rmask);  \
  DPP_ADD(d, ctrl, rmask)
#define WAVE_RED4(a, b, c, d)                                                 \
  do {                                                                        \
    LVL4(0x111, 0xf, a, b, c, d); LVL4(0x112, 0xf, a, b, c, d);               \
    LVL4(0x114, 0xf, a, b, c, d); LVL4(0x118, 0xf, a, b, c, d);               \
    LVL4(0x142, 0xa, a, b, c, d); LVL4(0x143, 0xc, a, b, c, d);               \
  } while (0)
#define WAVE_RED1(a)                                                          \
  do {                                                                        \
    DPP_ADD(a, 0x111, 0xf); DPP_ADD(a, 0x112, 0xf); DPP_ADD(a, 0x114, 0xf);  \
    DPP_ADD(a, 0x118, 0xf); DPP_ADD(a, 0x142, 0xa); DPP_ADD(a, 0x143, 0xc);  \
  } while (0)

__device__ __forceinline__ float rl63(float x) {
  return __builtin_bit_cast(
      float, __builtin_amdgcn_readlane(__builtin_bit_cast(int, x), 63));
}

// Async global->LDS DMA (no register writeback -> sound with regalloc).
#define GLL(idx, slot)                                                        \
  __builtin_amdgcn_global_load_lds(                                           \
      (const __attribute__((address_space(1))) void*)(hb + (size_t)(idx) * 64 + lane), \
      (__attribute__((address_space(3))) void*)&kring[(slot)][0], 4, 0, 0)

#define DSR(dst, a, offb)                                                     \
  asm volatile("ds_read_b128 %0, %1 offset:%2"                                \
               : "=&v"(dst) : "v"(a), "i"(offb))
#define DSRB64(dst, a, offb)                                                  \
  asm volatile("ds_read_b64 %0, %1 offset:%2"                                 \
               : "=&v"(dst) : "v"(a), "i"(offb))
#define DSW64(a, d, offb)                                                     \
  asm volatile("ds_write_b64 %0, %1 offset:%2"                                \
               :: "v"(a), "v"(d), "i"(offb) : "memory")
#define DSW32(a, d, offb)                                                     \
  asm volatile("ds_write_b32 %0, %1 offset:%2"                                \
               :: "v"(a), "v"(d), "i"(offb) : "memory")

// 4 reads = this wave's 16-col slice of one k vector -> register bank.
#define DSR4(B, slot)                                                         \
  do {                                                                        \
    unsigned _a = kb + (unsigned)(slot) * 256u + woff;                        \
    DSR(B[0], _a, 0); DSR(B[1], _a, 16); DSR(B[2], _a, 32); DSR(B[3], _a, 48);\
  } while (0)
#define DSR1(dst, slot)                                                       \
  do {                                                                        \
    unsigned _a1 = kb + (unsigned)(slot) * 256u + laneb;                      \
    asm volatile("ds_read_b32 %0, %1" : "=&v"(dst) : "v"(_a1));               \
  } while (0)

#define SB __builtin_amdgcn_sched_barrier(0)
#define WAIT_LGKM(n)                                                          \
  do { asm volatile("s_waitcnt lgkmcnt(" #n ")" ::: "memory"); SB; } while (0)
#define WAIT_VM(n)                                                            \
  do { asm volatile("s_waitcnt vmcnt(" #n ")" ::: "memory"); SB; } while (0)
#define KEEP4(BK)                                                             \
  asm volatile("" :: "v"(BK[0]), "v"(BK[1]), "v"(BK[2]), "v"(BK[3]))

// PAIR = R12's proven skeleton + ONE change: z-chains replicated in all 4
// waves -> gates resolve LOCALLY pre-barrier (no LDS on the gate path), and
// the M-update moves pre-barrier. scal carries only the 7 gram scalars
// (published pre-barrier at pair p = scalars for pair p+1; read post-barrier
// same pair; drained late via counted WAIT_LGKM(10), off the critical path).
// lgkm ledger: entry [NA4,NB4,eF,eG]=10 -> W(6) dots -> W(2) -> pdx(+1),
// pub(+1) -> W(0) -> barrier -> S,P(5) -> refills(8) + e(2) -> W(10) drains
// S,P -> exit queue = [refill8, e2] = 10. vm ledger identical to R12.
#define PAIR(UA, UB, NA, NB, PAR)                                             \
  do {                                                                        \
    float vp0 = A;                        /* vp_{t+1} | g_t=0 */              \
    float vp1 = fmaf(C_cur, u, A);        /* vp_{t+1} | g_t=1 */              \
    float u0 = fmaf(-r_nxt, vp0, e1);                                         \
    float u1 = fmaf(-r_nxt, vp1, e1);                                         \
    float wz = u  * fmaf(s2_cur, u,  2.0f * vp);                              \
    float z0 = u0 * fmaf(s2_nxt, u0, 2.0f * vp0);                             \
    float z1 = u1 * fmaf(s2_nxt, u1, 2.0f * vp1);                             \
    float pS2a = e2 * e2, pS2b = e3 * e3, pC2 = e2 * e3, pX02 = e2 * e4;      \
    float pC3 = e3 * e4, pX03 = e2 * e5, pX13 = e3 * e5;                      \
    WAIT_LGKM(6);   /* NA landed */                                           \
    float D1own, D2own;                                                       \
    {                                                                         \
      v4f x0 = __builtin_elementwise_fma(m4[0], NA[0], v4f{0.f,0.f,0.f,0.f}); \
      v4f x1 = __builtin_elementwise_fma(m4[1], NA[1], v4f{0.f,0.f,0.f,0.f}); \
      x0 = __builtin_elementwise_fma(m4[2], NA[2], x0);                       \
      x1 = __builtin_elementwise_fma(m4[3], NA[3], x1);                       \
      v4f xs = x0 + x1;                                                       \
      D1own = (xs.x + xs.y) + (xs.z + xs.w);                                  \
    }                                                                         \
    WAIT_LGKM(2);   /* NB landed; leaves [eF,eG] */                           \
    {                                                                         \
      v4f y0 = __builtin_elementwise_fma(m4[0], NB[0], v4f{0.f,0.f,0.f,0.f}); \
      v4f y1 = __builtin_elementwise_fma(m4[1], NB[1], v4f{0.f,0.f,0.f,0.f}); \
      y0 = __builtin_elementwise_fma(m4[2], NB[2], y0);                       \
      y1 = __builtin_elementwise_fma(m4[3], NB[3], y1);                       \
      v4f ys = y0 + y1;                                                       \
      D2own = (ys.x + ys.y) + (ys.z + ys.w);                                  \
    }                                                                         \
    DSW64(pdx_w, ((v2f){D1own, D2own}), (PAR) * 2048);                        \
    /* replicated z reduction + this wave's gram share */                     \
    if (w == 0)      { WAVE_RED5(wz, z0, z1, pS2a, pS2b); }                   \
    else if (w == 1) { WAVE_RED5(wz, z0, z1, pC2, pX02); }                    \
    else if (w == 2) { WAVE_RED5(wz, z0, z1, pC3, pX03); }                    \
    else             { WAVE_RED4(wz, z0, z1, pX13); }                         \
    if (lane == 63) {                                                         \
      if (w == 0)      DSW64(sc_pub, ((v2f){pS2a, pS2b}), (PAR) * 32);        \
      else if (w == 1) DSW64(sc_pub, ((v2f){pC2, pX02}), (PAR) * 32);         \
      else if (w == 2) DSW64(sc_pub, ((v2f){pC3, pX03}), (PAR) * 32);         \
      else             DSW32(sc_pub, pX13, (PAR) * 32);                       \
    }                                                                         \
    /* local gate resolve + M-update, all pre-barrier */                      \
    float zt = rl63(wz);                                                      \
    float z0s = rl63(z0), z1s = rl63(z1);                                     \
    bool gt = zt > 0.f;                                                       \
    float zsel = gt ? z1s : z0s;                                              \
    bool gt1 = zsel > 0.f;                                                    \
    float ga = gt ? u : 0.f;              /* g_t * u_t */                     \
    float usel = gt ? u1 : u0;                                                \
    float gb = gt1 ? usel : 0.f;          /* g_{t+1} * u_{t+1} */             \
    {                                                                         \
      v4f gav = {ga, ga, ga, ga};                                             \
      m4[0] = __builtin_elementwise_fma(gav, UA[0], m4[0]);                   \
      m4[1] = __builtin_elementwise_fma(gav, UA[1], m4[1]);                   \
      m4[2] = __builtin_elementwise_fma(gav, UA[2], m4[2]);                   \
      m4[3] = __builtin_elementwise_fma(gav, UA[3], m4[3]);                   \
      v4f gbv = {gb, gb, gb, gb};                                             \
      m4[0] = __builtin_elementwise_fma(gbv, UB[0], m4[0]);                   \
      m4[1] = __builtin_elementwise_fma(gbv, UB[1], m4[1]);                   \
      m4[2] = __builtin_elementwise_fma(gbv, UB[2], m4[2]);                   \
      m4[3] = __builtin_elementwise_fma(gbv, UB[3], m4[3]);                   \
    }                                                                         \
    WAIT_LGKM(0);                         /* pdx + pub + eF,eG drained */     \
    __builtin_amdgcn_s_barrier();                                             \
    SB;                                                                       \
    v4f S0, S1; v2f P0, P1, P2;                                               \
    DSR(S0, sc_a, (PAR) * 32 + 0);                                            \
    DSR(S1, sc_a, (PAR) * 32 + 16);                                           \
    DSRB64(P0, pdx_r0, (PAR) * 2048);                                         \
    DSRB64(P1, pdx_r1, (PAR) * 2048);                                         \
    DSRB64(P2, pdx_r2, (PAR) * 2048);     /* q = 5 */                         \
    WAIT_VM(6);     /* ring slots <= t+9 landed (R12 ledger) */               \
    DSR4(UA, (t + 4) & 31);   /* UA dead (update done) -> next pair's NA */   \
    DSR4(UB, (t + 5) & 31);               /* q = 13 */                        \
    float e2c = e2;                                                           \
    e1 = e3; e2 = e4; e3 = e5; e4 = eFp; e5 = eGp;                            \
    DSR1(eFp, (t + 8) & 31);                                                  \
    DSR1(eGp, (t + 9) & 31);              /* q = 15 */                        \
    {                                                                         \
      int i0 = t + 16; if (i0 > LM1) i0 = LM1;                                \
      int i1 = t + 17; if (i1 > LM1) i1 = LM1;                                \
      GLL(i0, (t + 16) & 31);                                                 \
      GLL(i1, (t + 17) & 31);                                                 \
    }                                                                         \
    WAIT_LGKM(10);  /* drains S,P; leaves [refill8, e2] = 10 = entry */       \
    float D1 = (D1own + P0.x) + (P1.x + P2.x);                                \
    float D2 = (D2own + P0.y) + (P1.y + P2.y);                                \
    float vp_n = fmaf(C_nxt, gb, fmaf(X02, ga, D1));  /* vp_{t+2} */          \
    float A_n  = fmaf(X13,  gb, fmaf(X03, ga, D2));   /* M_{t+2} k_{t+3} */   \
    float u_n  = fmaf(-(1.0f / (S0.x + EPS)), vp_n, e2c);  /* u_{t+2} */      \
    s2_cur = S0.x; s2_nxt = S0.y; r_nxt = 1.0f / (S0.y + EPS);                \
    C_cur = S0.z; C_nxt = S1.x;                                               \
    X02 = S0.w; X03 = S1.y; X13 = S1.z;                                       \
    vp = vp_n; u = u_n; A = A_n;                                              \
    t += 2;                                                                   \
  } while (0)

// One block = 4 waves = one batch chain. Lane i owns row i of M; wave w owns
// columns [16w, 16w+16). R12 structure; gates now resolve locally.
__global__ __launch_bounds__(256, 1)
void delta_mem_seq(const float* __restrict__ h,
                   const float* __restrict__ W,
                   const float* __restrict__ bias,
                   float* __restrict__ out,
                   int L) {
  const int tid = threadIdx.x;
  const int w = tid >> 6;
  const int lane = tid & 63;
  __shared__ alignas(16) float kring[32][64];   // 8 KB ring
  __shared__ alignas(16) v2f pdx[2][4][64];     // dot partials (parity dbuf)
  __shared__ alignas(16) float scal[2][8];      // published gram scalars
  __shared__ alignas(16) float rbuf[64];
  const float* __restrict__ hb = h + (size_t)blockIdx.x * (size_t)L * 64;
  const int LM1 = L - 1;  // gates t = 0..LM1-1

  const unsigned kb = (unsigned)(unsigned long long)
      (__attribute__((address_space(3))) const float*)&kring[0][0];
  const unsigned woff = (unsigned)(w << 6);
  const unsigned laneb = (unsigned)(lane << 2);
  const unsigned pb = (unsigned)(unsigned long long)
      (__attribute__((address_space(3))) const v2f*)&pdx[0][0][0];
  const unsigned pdx_w  = pb + (unsigned)(w << 9) + (unsigned)(lane << 3);
  const unsigned pdx_r0 = pb + (unsigned)(((w + 1) & 3) << 9) + (unsigned)(lane << 3);
  const unsigned pdx_r1 = pb + (unsigned)(((w + 2) & 3) << 9) + (unsigned)(lane << 3);
  const unsigned pdx_r2 = pb + (unsigned)(((w + 3) & 3) << 9) + (unsigned)(lane << 3);
  const unsigned sc_a = (unsigned)(unsigned long long)
      (__attribute__((address_space(3))) const float*)&scal[0][0];
  const unsigned sc_pub = sc_a + (unsigned)(w << 3);

  v4f m4[4];  // M[lane][16w .. 16w+15]
#pragma unroll
  for (int q = 0; q < 4; ++q) m4[q] = v4f{0.f, 0.f, 0.f, 0.f};

  // Prologue: fill ring slots 0..15 (all waves duplicate -> wave-local vmcnt).
#pragma unroll
  for (int i = 0; i < 16; ++i) {
    int idx = (i <= LM1) ? i : LM1;
    GLL(idx, i);
  }
  WAIT_VM(0);

  float e1 = kring[1][lane], e2 = kring[2][lane];
  float e3 = kring[3][lane], e4 = kring[4][lane], e5 = kring[5][lane];
  float e0 = kring[0][lane];

  // Prologue reductions: pair-0 actives only (7 chains).
  float c0 = e0 * e0, c1 = e1 * e1, c2 = e0 * e1, c3 = e1 * e2;
  float c4 = e0 * e2, c5 = e0 * e3, c6 = e1 * e3;
  float c7 = 0.f, c8 = 0.f, c9 = 0.f;
  WAVE_RED10(c0, c1, c2, c3, c4, c5, c6, c7, c8, c9);
  float s2_cur = rl63(c0), s2_nxt = rl63(c1);
  float C_cur = rl63(c2), C_nxt = rl63(c3);
  float X02 = rl63(c4), X03 = rl63(c5), X13 = rl63(c6);
  float r_nxt = 1.0f / (s2_nxt + EPS);
  float vp = 0.f;  // vp_0 = M_0 k_0 = 0
  float u = e0;    // u_0 = k_0
  float A = 0.f;   // M_0 k_1 = 0
  int t = 0;

  // Register banks: U = slots 0,1 (first update), drained; N = slots 2,3 and
  // e-prefetch slots 6,7 left IN FLIGHT -> loop-entry queue = 10 (R12).
  v4f U0[4], U1[4], N0[4], N1[4];
  float eFp, eGp;
  SB;
  DSR4(U0, 0); DSR4(U1, 1);
  WAIT_LGKM(0);
  DSR4(N0, 2); DSR4(N1, 3);
  DSR1(eFp, 6); DSR1(eGp, 7);
  SB;            // queue = [N0 x4, N1 x4, eFp, eGp] = 10

  while (t + 3 < LM1) {   // 2x unrolled bank-role rotation; PAR alternates
    PAIR(U0, U1, N0, N1, 0);
    PAIR(N0, N1, U0, U1, 1);
  }
  if (t + 1 < LM1) PAIR(U0, U1, N0, N1, 0);

  // Drain ALL in-flight ds_reads/DMAs; keep dsts formally live (R5-R7 lesson).
  asm volatile("s_waitcnt vmcnt(0) lgkmcnt(0)" ::: "memory");
  SB;
  KEEP4(U0); KEEP4(U1); KEEP4(N0); KEEP4(N1);
  asm volatile("" :: "v"(eFp), "v"(eGp));

  if (t < LM1) {  // odd leftover gate (replicated in all waves)
    float wz = u * fmaf(s2_cur, u, 2.0f * vp);
    WAVE_RED1(wz);
    float zt = rl63(wz);
    float coef = (zt > 0.f) ? C_cur : 0.f;
    vp = fmaf(coef, u, A);  // read = M_L k_{L-1}
  }

  if (w == 0) rbuf[lane] = vp;
  __syncthreads();

  if (w == 0) {
    const v4f* wv = (const v4f*)(W + lane * 64);
    const v4f* rv = (const v4f*)rbuf;
    v4f acc = v4f{0.f, 0.f, 0.f, 0.f};
#pragma unroll
    for (int q = 0; q < 16; ++q)
      acc = __builtin_elementwise_fma(wv[q], rv[q], acc);
    out[(size_t)blockIdx.x * 64 + lane] =
        bias[lane] + ((acc.x + acc.y) + (acc.z + acc.w));
  }
}

extern "C" void kernel_launch(void* const* d_in, const int* in_sizes, int n_in,
                              void* d_out, int out_size, void* d_ws, size_t ws_size,
                              hipStream_t stream) {
  const float* h    = (const float*)d_in[0];
  const float* W    = (const float*)d_in[1];
  const float* bias = (const float*)d_in[2];
  float* out = (float*)d_out;

  const int H = in_sizes[2];            // 64
  const int B = out_size / H;           // 256
  const int L = in_sizes[0] / (B * H);  // 2048

  delta_mem_seq<<<B, 256, 0, stream>>>(h, W, bias, out, L);
}

// Round 16
// 725.729 us; speedup vs baseline: 1.2232x; 1.2232x over previous
//
#include <hip/hip_runtime.h>

typedef float v4f __attribute__((ext_vector_type(4)));
typedef float v2f __attribute__((ext_vector_type(2)));
static constexpr float EPS = 1e-6f;

// DPP partial-sum step: x += dpp_move(x); out-of-bounds lanes contribute 0.
#define DPP_ADD(x, ctrl, rmask)                                               \
  x += __builtin_bit_cast(float, __builtin_amdgcn_update_dpp(                 \
           0, __builtin_bit_cast(int, x), ctrl, rmask, 0xf, true))

#define LVL10(ctrl, rmask, a, b, c, d, e, f, g, h, i, j)                      \
  DPP_ADD(a, ctrl, rmask); DPP_ADD(b, ctrl, rmask); DPP_ADD(c, ctrl, rmask);  \
  DPP_ADD(d, ctrl, rmask); DPP_ADD(e, ctrl, rmask); DPP_ADD(f, ctrl, rmask);  \
  DPP_ADD(g, ctrl, rmask); DPP_ADD(h, ctrl, rmask); DPP_ADD(i, ctrl, rmask);  \
  DPP_ADD(j, ctrl, rmask)
#define WAVE_RED10(a, b, c, d, e, f, g, h, i, j)                              \
  do {                                                                        \
    LVL10(0x111, 0xf, a, b, c, d, e, f, g, h, i, j);                          \
    LVL10(0x112, 0xf, a, b, c, d, e, f, g, h, i, j);                          \
    LVL10(0x114, 0xf, a, b, c, d, e, f, g, h, i, j);                          \
    LVL10(0x118, 0xf, a, b, c, d, e, f, g, h, i, j);                          \
    LVL10(0x142, 0xa, a, b, c, d, e, f, g, h, i, j);                          \
    LVL10(0x143, 0xc, a, b, c, d, e, f, g, h, i, j);                          \
  } while (0)
#define WAVE_RED3(a, b, c)                                                    \
  do {                                                                        \
    DPP_ADD(a, 0x111, 0xf); DPP_ADD(b, 0x111, 0xf); DPP_ADD(c, 0x111, 0xf);  \
    DPP_ADD(a, 0x112, 0xf); DPP_ADD(b, 0x112, 0xf); DPP_ADD(c, 0x112, 0xf);  \
    DPP_ADD(a, 0x114, 0xf); DPP_ADD(b, 0x114, 0xf); DPP_ADD(c, 0x114, 0xf);  \
    DPP_ADD(a, 0x118, 0xf); DPP_ADD(b, 0x118, 0xf); DPP_ADD(c, 0x118, 0xf);  \
    DPP_ADD(a, 0x142, 0xa); DPP_ADD(b, 0x142, 0xa); DPP_ADD(c, 0x142, 0xa);  \
    DPP_ADD(a, 0x143, 0xc); DPP_ADD(b, 0x143, 0xc); DPP_ADD(c, 0x143, 0xc);  \
  } while (0)
#define WAVE_RED2(a, b)                                                       \
  do {                                                                        \
    DPP_ADD(a, 0x111, 0xf); DPP_ADD(b, 0x111, 0xf);                           \
    DPP_ADD(a, 0x112, 0xf); DPP_ADD(b, 0x112, 0xf);                           \
    DPP_ADD(a, 0x114, 0xf); DPP_ADD(b, 0x114, 0xf);                           \
    DPP_ADD(a, 0x118, 0xf); DPP_ADD(b, 0x118, 0xf);                           \
    DPP_ADD(a, 0x142, 0xa); DPP_ADD(b, 0x142, 0xa);                           \
    DPP_ADD(a, 0x143, 0xc); DPP_ADD(b, 0x143, 0xc);                           \
  } while (0)
#define WAVE_RED1(a)                                                          \
  do {                                                                        \
    DPP_ADD(a, 0x111, 0xf); DPP_ADD(a, 0x112, 0xf); DPP_ADD(a, 0x114, 0xf);  \
    DPP_ADD(a, 0x118, 0xf); DPP_ADD(a, 0x142, 0xa); DPP_ADD(a, 0x143, 0xc);  \
  } while (0)

__device__ __forceinline__ float rl63(float x) {
  return __builtin_bit_cast(
      float, __builtin_amdgcn_readlane(__builtin_bit_cast(int, x), 63));
}

// Async global->LDS DMA (no register writeback -> sound with regalloc).
#define GLL(idx, slot)                                                        \
  __builtin_amdgcn_global_load_lds(                                           \
      (const __attribute__((address_space(1))) void*)(hb + (size_t)(idx) * 64 + lane), \
      (__attribute__((address_space(3))) void*)&kring[(slot)][0], 4, 0, 0)

#define DSR(dst, a, offb)                                                     \
  asm volatile("ds_read_b128 %0, %1 offset:%2"                                \
               : "=&v"(dst) : "v"(a), "i"(offb))
#define DSRB64(dst, a, offb)                                                  \
  asm volatile("ds_read_b64 %0, %1 offset:%2"                                 \
               : "=&v"(dst) : "v"(a), "i"(offb))
#define DSW64(a, d, offb)                                                     \
  asm volatile("ds_write_b64 %0, %1 offset:%2"                                \
               :: "v"(a), "v"(d), "i"(offb) : "memory")
#define DSW32(a, d, offb)                                                     \
  asm volatile("ds_write_b32 %0, %1 offset:%2"                                \
               :: "v"(a), "v"(d), "i"(offb) : "memory")

// 4 reads = this wave's 16-col slice of one k vector -> register bank.
#define DSR4(B, slot)                                                         \
  do {                                                                        \
    unsigned _a = kb + (unsigned)(slot) * 256u + woff;                        \
    DSR(B[0], _a, 0); DSR(B[1], _a, 16); DSR(B[2], _a, 32); DSR(B[3], _a, 48);\
  } while (0)
#define DSR1(dst, slot)                                                       \
  do {                                                                        \
    unsigned _a1 = kb + (unsigned)(slot) * 256u + laneb;                      \
    asm volatile("ds_read_b32 %0, %1" : "=&v"(dst) : "v"(_a1));               \
  } while (0)

#define SB __builtin_amdgcn_sched_barrier(0)
#define WAIT_LGKM(n)                                                          \
  do { asm volatile("s_waitcnt lgkmcnt(" #n ")" ::: "memory"); SB; } while (0)
#define WAIT_VM(n)                                                            \
  do { asm volatile("s_waitcnt vmcnt(" #n ")" ::: "memory"); SB; } while (0)
#define KEEP4(BK)                                                             \
  asm volatile("" :: "v"(BK[0]), "v"(BK[1]), "v"(BK[2]), "v"(BK[3]))

// PAIR = R12 (718 us, proven) with three scheduling deltas, no algebra change:
//  (1) post-barrier S-wait split: WAIT(5) drains only S0 (gate inputs) with
//      WAIT_VM+GLL issues interposed as cover;
//  (2) M-update + UA/UB refill immediately after gates -> next pair's bank
//      drains (WAIT 6/2) have a full-pair of cover (were ~90 cy in R12);
//  (3) S1/S2/P drains moved late (WAIT(8) after refill issue).
// lgkm ledger: entry [refill8, eF, eG]=10 (or 0 after a backedge drain; both
// states safe) -> W(6) drains NA -> W(2) drains NB -> pdx +1, pubs +1..2 ->
// W(0) -> barrier -> S3+P3 issues=6 -> W(5) drains S0 -> gates, update,
// refill8 (q=13) -> W(8) drains S1,S2,P -> e-rot, e-issues (q=10) -> end.
// vm ledger (R12): entry<=8 -> WAIT_VM(6) -> GLL x2 -> 8.
#define PAIR(UA, UB, NA, NB, PAR)                                             \
  do {                                                                        \
    float vp0 = A;                        /* vp_{t+1} | g_t=0 */              \
    float vp1 = fmaf(C_cur, u, A);        /* vp_{t+1} | g_t=1 */              \
    float u0 = fmaf(-r_nxt, vp0, e1);                                         \
    float u1 = fmaf(-r_nxt, vp1, e1);                                         \
    float wz = u  * fmaf(s2_cur, u,  2.0f * vp);                              \
    float z0 = u0 * fmaf(s2_nxt, u0, 2.0f * vp0);                             \
    float z1 = u1 * fmaf(s2_nxt, u1, 2.0f * vp1);                             \
    float pS2a = e2 * e2, pS2b = e3 * e3, pC2 = e2 * e3, pX02 = e2 * e4;      \
    float pC3 = e3 * e4, pX03 = e2 * e5, pX13 = e3 * e5;                      \
    WAIT_LGKM(6);   /* NA landed (refilled LAST pair mid-body: full cover) */ \
    float D1own, D2own;                                                       \
    {                                                                         \
      v4f x0 = __builtin_elementwise_fma(m4[0], NA[0], v4f{0.f,0.f,0.f,0.f}); \
      v4f x1 = __builtin_elementwise_fma(m4[1], NA[1], v4f{0.f,0.f,0.f,0.f}); \
      x0 = __builtin_elementwise_fma(m4[2], NA[2], x0);                       \
      x1 = __builtin_elementwise_fma(m4[3], NA[3], x1);                       \
      v4f xs = x0 + x1;                                                       \
      D1own = (xs.x + xs.y) + (xs.z + xs.w);                                  \
    }                                                                         \
    WAIT_LGKM(2);   /* NB landed; leaves [eF,eG] */                           \
    {                                                                         \
      v4f y0 = __builtin_elementwise_fma(m4[0], NB[0], v4f{0.f,0.f,0.f,0.f}); \
      v4f y1 = __builtin_elementwise_fma(m4[1], NB[1], v4f{0.f,0.f,0.f,0.f}); \
      y0 = __builtin_elementwise_fma(m4[2], NB[2], y0);                       \
      y1 = __builtin_elementwise_fma(m4[3], NB[3], y1);                       \
      v4f ys = y0 + y1;                                                       \
      D2own = (ys.x + ys.y) + (ys.z + ys.w);                                  \
    }                                                                         \
    DSW64(pdx_w, ((v2f){D1own, D2own}), (PAR) * 2048);                        \
    if (w == 0) {       /* chains: z_t, z_{t+1}|0, z_{t+1}|1 */               \
      WAVE_RED3(wz, z0, z1);                                                  \
      if (lane == 63) {                                                       \
        DSW64(sc_a, ((v2f){wz, z0}), (PAR) * 48 + 0);                         \
        DSW32(sc_a, z1, (PAR) * 48 + 8);                                      \
      }                                                                       \
    } else if (w == 1) {  /* s2_{t+2}, s2_{t+3}, C_{t+1} */                   \
      WAVE_RED3(pS2a, pS2b, pC2);                                             \
      if (lane == 63) {                                                       \
        DSW32(sc_a, pS2a, (PAR) * 48 + 12);                                   \
        DSW64(sc_a, ((v2f){pS2b, pC2}), (PAR) * 48 + 16);                     \
      }                                                                       \
    } else if (w == 2) {  /* X02', C3' */                                     \
      WAVE_RED2(pX02, pC3);                                                   \
      if (lane == 63) DSW64(sc_a, ((v2f){pX02, pC3}), (PAR) * 48 + 24);       \
    } else {              /* X03', X13' */                                    \
      WAVE_RED2(pX03, pX13);                                                  \
      if (lane == 63) DSW64(sc_a, ((v2f){pX03, pX13}), (PAR) * 48 + 32);      \
    }                                                                         \
    WAIT_LGKM(0);   /* pdx + pubs + eF,eG drained; queue = 0 at barrier */    \
    __builtin_amdgcn_s_barrier();                                             \
    SB;                                                                       \
    v4f S0, S1; v2f S2, P0, P1, P2;                                           \
    DSR(S0, sc_a, (PAR) * 48 + 0);                                            \
    DSR(S1, sc_a, (PAR) * 48 + 16);                                           \
    DSRB64(S2, sc_a, (PAR) * 48 + 32);                                        \
    DSRB64(P0, pdx_r0, (PAR) * 2048);                                         \
    DSRB64(P1, pdx_r1, (PAR) * 2048);                                         \
    DSRB64(P2, pdx_r2, (PAR) * 2048);     /* q = 6 */                         \
    WAIT_VM(6);     /* ring slots <= t+9 landed (issued >= 3 pairs ago) */    \
    {                                                                         \
      int i0 = t + 16; if (i0 > LM1) i0 = LM1;                                \
      int i1 = t + 17; if (i1 > LM1) i1 = LM1;                                \
      GLL(i0, (t + 16) & 31);                                                 \
      GLL(i1, (t + 17) & 31);                                                 \
    }                                                                         \
    WAIT_LGKM(5);   /* S0 landed (DS in-order) — gate inputs only */          \
    float zt = S0.x, z0s = S0.y, z1s = S0.z, s2a = S0.w;                      \
    bool gt = zt > 0.f;                                                       \
    float zsel = gt ? z1s : z0s;                                              \
    bool gt1 = zsel > 0.f;                                                    \
    float ga = gt ? u : 0.f;                /* g_t * u_t */                   \
    float usel = gt ? u1 : u0;                                                \
    float gb = gt1 ? usel : 0.f;            /* g_{t+1} * u_{t+1} */           \
    float r2 = 1.0f / (s2a + EPS);                                            \
    {                                                                         \
      v4f gav = {ga, ga, ga, ga};                                             \
      m4[0] = __builtin_elementwise_fma(gav, UA[0], m4[0]);                   \
      m4[1] = __builtin_elementwise_fma(gav, UA[1], m4[1]);                   \
      m4[2] = __builtin_elementwise_fma(gav, UA[2], m4[2]);                   \
      m4[3] = __builtin_elementwise_fma(gav, UA[3], m4[3]);                   \
      v4f gbv = {gb, gb, gb, gb};                                             \
      m4[0] = __builtin_elementwise_fma(gbv, UB[0], m4[0]);                   \
      m4[1] = __builtin_elementwise_fma(gbv, UB[1], m4[1]);                   \
      m4[2] = __builtin_elementwise_fma(gbv, UB[2], m4[2]);                   \
      m4[3] = __builtin_elementwise_fma(gbv, UB[3], m4[3]);                   \
    }                                                                         \
    DSR4(UA, (t + 4) & 31);   /* UA dead -> next pair's NA (early refill) */  \
    DSR4(UB, (t + 5) & 31);               /* q = 5 + 8 = 13 */                \
    WAIT_LGKM(8);   /* drains S1,S2,P0..P2; leaves refill8 */                 \
    float s2b = S1.x, C2s = S1.y, X02n = S1.z, C3s = S1.w;                    \
    float X03n = S2.x, X13n = S2.y;                                           \
    float D1 = (D1own + P0.x) + (P1.x + P2.x);                                \
    float D2 = (D2own + P0.y) + (P1.y + P2.y);                                \
    float vp_n = fmaf(C_nxt, gb, fmaf(X02, ga, D1));  /* vp_{t+2} */          \
    float A_n  = fmaf(X13,  gb, fmaf(X03, ga, D2));   /* M_{t+2} k_{t+3} */   \
    float u_n  = fmaf(-r2, vp_n, e2);                 /* u_{t+2} */           \
    e1 = e3; e2 = e4; e3 = e5; e4 = eFp; e5 = eGp;    /* old eF,eG drained */ \
    DSR1(eFp, (t + 8) & 31);                                                  \
    DSR1(eGp, (t + 9) & 31);              /* q = 10 across pair boundary */   \
    s2_cur = s2a; s2_nxt = s2b; r_nxt = 1.0f / (s2b + EPS);                   \
    C_cur = C2s; C_nxt = C3s; X02 = X02n; X03 = X03n; X13 = X13n;             \
    vp = vp_n; u = u_n; A = A_n;                                              \
    t += 2;                                                                   \
  } while (0)

// One block = 4 waves = one batch chain. Lane i owns row i of M; wave w owns
// columns [16w, 16w+16). R12 structure + scheduling deltas (see PAIR).
__global__ __launch_bounds__(256, 1)
void delta_mem_seq(const float* __restrict__ h,
                   const float* __restrict__ W,
                   const float* __restrict__ bias,
                   float* __restrict__ out,
                   int L) {
  const int tid = threadIdx.x;
  const int w = tid >> 6;
  const int lane = tid & 63;
  __shared__ alignas(16) float kring[32][64];   // 8 KB ring
  __shared__ alignas(16) v2f pdx[2][4][64];     // dot partials (parity dbuf)
  __shared__ alignas(16) float scal[2][12];     // published reduction scalars
  __shared__ alignas(16) float rbuf[64];
  const float* __restrict__ hb = h + (size_t)blockIdx.x * (size_t)L * 64;
  const int LM1 = L - 1;  // gates t = 0..LM1-1

  const unsigned kb = (unsigned)(unsigned long long)
      (__attribute__((address_space(3))) const float*)&kring[0][0];
  const unsigned woff = (unsigned)(w << 6);
  const unsigned laneb = (unsigned)(lane << 2);
  const unsigned pb = (unsigned)(unsigned long long)
      (__attribute__((address_space(3))) const v2f*)&pdx[0][0][0];
  const unsigned pdx_w  = pb + (unsigned)(w << 9) + (unsigned)(lane << 3);
  const unsigned pdx_r0 = pb + (unsigned)(((w + 1) & 3) << 9) + (unsigned)(lane << 3);
  const unsigned pdx_r1 = pb + (unsigned)(((w + 2) & 3) << 9) + (unsigned)(lane << 3);
  const unsigned pdx_r2 = pb + (unsigned)(((w + 3) & 3) << 9) + (unsigned)(lane << 3);
  const unsigned sc_a = (unsigned)(unsigned long long)
      (__attribute__((address_space(3))) const float*)&scal[0][0];

  v4f m4[4];  // M[lane][16w .. 16w+15]
#pragma unroll
  for (int q = 0; q < 4; ++q) m4[q] = v4f{0.f, 0.f, 0.f, 0.f};

  // Prologue: fill ring slots 0..15 (all waves duplicate -> wave-local vmcnt).
#pragma unroll
  for (int i = 0; i < 16; ++i) {
    int idx = (i <= LM1) ? i : LM1;
    GLL(idx, i);
  }
  WAIT_VM(0);

  float e0 = kring[0][lane];
  float e1 = kring[1][lane], e2 = kring[2][lane], e3 = kring[3][lane];
  float e4 = kring[4][lane], e5 = kring[5][lane];

  // Prologue reductions: s2_0, s2_1, C_0, C_1, X02, X03, X13 (replicated).
  float c0 = e0 * e0, c1 = e1 * e1, c2 = e0 * e1, c3 = e1 * e2;
  float c4 = e0 * e2, c5 = e0 * e3, c6 = e1 * e3;
  float c7 = 0.f, c8 = 0.f, c9 = 0.f;
  WAVE_RED10(c0, c1, c2, c3, c4, c5, c6, c7, c8, c9);
  float s2_cur = rl63(c0), s2_nxt = rl63(c1);
  float C_cur = rl63(c2), C_nxt = rl63(c3);
  float X02 = rl63(c4), X03 = rl63(c5), X13 = rl63(c6);
  float r_nxt = 1.0f / (s2_nxt + EPS);
  float vp = 0.f;  // vp_0 = M_0 k_0 = 0
  float u = e0;    // u_0 = k_0
  float A = 0.f;   // M_0 k_1 = 0
  int t = 0;

  // Register banks: U = slots 0,1 (first update), drained; N = slots 2,3 and
  // e-prefetch slots 6,7 left IN FLIGHT -> loop-entry queue = 10 (R12).
  v4f U0[4], U1[4], N0[4], N1[4];
  float eFp, eGp;
  SB;
  DSR4(U0, 0); DSR4(U1, 1);
  WAIT_LGKM(0);
  DSR4(N0, 2); DSR4(N1, 3);
  DSR1(eFp, 6); DSR1(eGp, 7);
  SB;            // queue = [N0 x4, N1 x4, eFp, eGp] = 10

  while (t + 3 < LM1) {   // 2x unrolled bank-role rotation; PAR alternates
    PAIR(U0, U1, N0, N1, 0);
    PAIR(N0, N1, U0, U1, 1);
    WAIT_LGKM(0);  // backedge drain: no in-flight asm dsts cross the branch
    SB;
  }
  if (t + 1 < LM1) {
    PAIR(U0, U1, N0, N1, 0);
    WAIT_LGKM(0);
    SB;
  }

  // Drain ALL in-flight DMAs; keep dsts formally live (R5-R7 lesson).
  asm volatile("s_waitcnt vmcnt(0) lgkmcnt(0)" ::: "memory");
  SB;
  KEEP4(U0); KEEP4(U1); KEEP4(N0); KEEP4(N1);
  asm volatile("" :: "v"(eFp), "v"(eGp));

  if (t < LM1) {  // odd leftover gate (replicated in all waves)
    float wz = u * fmaf(s2_cur, u, 2.0f * vp);
    WAVE_RED1(wz);
    float zt = rl63(wz);
    float coef = (zt > 0.f) ? C_cur : 0.f;
    vp = fmaf(coef, u, A);  // read = M_L k_{L-1}
  }

  if (w == 0) rbuf[lane] = vp;
  __syncthreads();

  if (w == 0) {
    const v4f* wv = (const v4f*)(W + lane * 64);
    const v4f* rv = (const v4f*)rbuf;
    v4f acc = v4f{0.f, 0.f, 0.f, 0.f};
#pragma unroll
    for (int q = 0; q < 16; ++q)
      acc = __builtin_elementwise_fma(wv[q], rv[q], acc);
    out[(size_t)blockIdx.x * 64 + lane] =
        bias[lane] + ((acc.x + acc.y) + (acc.z + acc.w));
  }
}

extern "C" void kernel_launch(void* const* d_in, const int* in_sizes, int n_in,
                              void* d_out, int out_size, void* d_ws, size_t ws_size,
                              hipStream_t stream) {
  const float* h    = (const float*)d_in[0];
  const float* W    = (const float*)d_in[1];
  const float* bias = (const float*)d_in[2];
  float* out = (float*)d_out;

  const int H = in_sizes[2];            // 64
  const int B = out_size / H;           // 256
  const int L = in_sizes[0] / (B * H);  // 2048

  delta_mem_seq<<<B, 256, 0, stream>>>(h, W, bias, out, L);
}

// Round 17
// 714.392 us; speedup vs baseline: 1.2426x; 1.0159x over previous
//
#include <hip/hip_runtime.h>

typedef float v4f __attribute__((ext_vector_type(4)));
typedef float v2f __attribute__((ext_vector_type(2)));
static constexpr float EPS = 1e-6f;

// DPP partial-sum step: x += dpp_move(x); out-of-bounds lanes contribute 0.
#define DPP_ADD(x, ctrl, rmask)                                               \
  x += __builtin_bit_cast(float, __builtin_amdgcn_update_dpp(                 \
           0, __builtin_bit_cast(int, x), ctrl, rmask, 0xf, true))

#define WAVE_RED1(a)                                                          \
  do {                                                                        \
    DPP_ADD(a, 0x111, 0xf); DPP_ADD(a, 0x112, 0xf); DPP_ADD(a, 0x114, 0xf);  \
    DPP_ADD(a, 0x118, 0xf); DPP_ADD(a, 0x142, 0xa); DPP_ADD(a, 0x143, 0xc);  \
  } while (0)

__device__ __forceinline__ float rl63(float x) {
  return __builtin_bit_cast(
      float, __builtin_amdgcn_readlane(__builtin_bit_cast(int, x), 63));
}
__device__ __forceinline__ float hsum4(v4f v) {
  return (v.x + v.y) + (v.z + v.w);
}

// Async global->LDS DMA (no register writeback -> sound with regalloc).
#define GLL(idx, slot)                                                        \
  __builtin_amdgcn_global_load_lds(                                           \
      (const __attribute__((address_space(1))) void*)(hb + (size_t)(idx) * 64 + lane), \
      (__attribute__((address_space(3))) void*)&kring[(slot)][0], 4, 0, 0)

#define DSR(dst, a, offb)                                                     \
  asm volatile("ds_read_b128 %0, %1 offset:%2"                                \
               : "=&v"(dst) : "v"(a), "i"(offb))
#define DSRB64(dst, a, offb)                                                  \
  asm volatile("ds_read_b64 %0, %1 offset:%2"                                 \
               : "=&v"(dst) : "v"(a), "i"(offb))
#define DSW64(a, d, offb)                                                     \
  asm volatile("ds_write_b64 %0, %1 offset:%2"                                \
               :: "v"(a), "v"(d), "i"(offb) : "memory")
#define DSW32(a, d, offb)                                                     \
  asm volatile("ds_write_b32 %0, %1 offset:%2"                                \
               :: "v"(a), "v"(d), "i"(offb) : "memory")

// 4 reads = this wave's 16-col slice of one k vector -> register bank.
#define DSR4(B, slot)                                                         \
  do {                                                                        \
    unsigned _a = kb + (unsigned)(slot) * 256u + woff;                        \
    DSR(B[0], _a, 0); DSR(B[1], _a, 16); DSR(B[2], _a, 32); DSR(B[3], _a, 48);\
  } while (0)
#define DSR1(dst, slot)                                                       \
  do {                                                                        \
    unsigned _a1 = kb + (unsigned)(slot) * 256u + laneb;                      \
    asm volatile("ds_read_b32 %0, %1" : "=&v"(dst) : "v"(_a1));               \
  } while (0)

#define SB __builtin_amdgcn_sched_barrier(0)
#define WAIT_LGKM(n)                                                          \
  do { asm volatile("s_waitcnt lgkmcnt(" #n ")" ::: "memory"); SB; } while (0)
#define WAIT_VM(n)                                                            \
  do { asm volatile("s_waitcnt vmcnt(" #n ")" ::: "memory"); SB; } while (0)
#define KEEP4(BK)                                                             \
  asm volatile("" :: "v"(BK[0]), "v"(BK[1]), "v"(BK[2]), "v"(BK[3]))

// PAIR (steps t, t+1). Gram scalars come from the precomputed LDS table
// (NO per-pair Gram reductions): only 3 z-chains remain, one per wave
// (RED1 = 6 DPP max/wave vs R12's 18 — the measured dominant cost).
// lgkm ledger (uniform; w3 publishes a dummy): entry [R8] (or 0 after
// backedge drain; waits safe both ways) -> W(4) NA -> W(0) NB -> pdx(1),
// zpub(2) -> W(0) -> barrier -> S(1),P3(4),eF,eG(6),GA,GB(8) -> W(4)
// drains S,P -> gates, update -> refills(12) -> W(8) drains e,G ->
// recurrences -> exit [R8]. vm ledger = R16: entry<=8 -> WAIT_VM(6) ->
// GLL x2 -> 8 (slots <= t+11 landed; reads need <= t+5).
#define PAIR(UA, UB, NA, NB, PAR)                                             \
  do {                                                                        \
    float vp0 = A;                        /* vp_{t+1} | g_t=0 */              \
    float vp1 = fmaf(C_cur, u, A);        /* vp_{t+1} | g_t=1 */              \
    float u0 = fmaf(-r_nxt, vp0, e1);                                         \
    float u1 = fmaf(-r_nxt, vp1, e1);                                         \
    float wz = u  * fmaf(s2_cur, u,  2.0f * vp);                              \
    float z0 = u0 * fmaf(s2_nxt, u0, 2.0f * vp0);                             \
    float z1 = u1 * fmaf(s2_nxt, u1, 2.0f * vp1);                             \
    WAIT_LGKM(4);   /* NA landed (refilled last pair: full cover) */          \
    float D1own, D2own;                                                       \
    {                                                                         \
      v4f x0 = __builtin_elementwise_fma(m4[0], NA[0], v4f{0.f,0.f,0.f,0.f}); \
      v4f x1 = __builtin_elementwise_fma(m4[1], NA[1], v4f{0.f,0.f,0.f,0.f}); \
      x0 = __builtin_elementwise_fma(m4[2], NA[2], x0);                       \
      x1 = __builtin_elementwise_fma(m4[3], NA[3], x1);                       \
      D1own = hsum4(x0 + x1);                                                 \
    }                                                                         \
    WAIT_LGKM(0);   /* NB landed */                                           \
    {                                                                         \
      v4f y0 = __builtin_elementwise_fma(m4[0], NB[0], v4f{0.f,0.f,0.f,0.f}); \
      v4f y1 = __builtin_elementwise_fma(m4[1], NB[1], v4f{0.f,0.f,0.f,0.f}); \
      y0 = __builtin_elementwise_fma(m4[2], NB[2], y0);                       \
      y1 = __builtin_elementwise_fma(m4[3], NB[3], y1);                       \
      D2own = hsum4(y0 + y1);                                                 \
    }                                                                         \
    DSW64(pdx_w, ((v2f){D1own, D2own}), (PAR) * 2048);                        \
    /* one z-chain per wave; w3 reduces nothing, publishes a dummy */         \
    if (w == 0)      { WAVE_RED1(wz); }                                       \
    else if (w == 1) { WAVE_RED1(z0); }                                       \
    else if (w == 2) { WAVE_RED1(z1); }                                       \
    if (lane == 63) {                                                         \
      float pubv = (w == 0) ? wz : (w == 1) ? z0 : (w == 2) ? z1 : wz;        \
      DSW32(sc_pub, pubv, (PAR) * 16);                                        \
    }                                                                         \
    WAIT_LGKM(0);   /* pdx + pub drained; queue = 0 at barrier */             \
    __builtin_amdgcn_s_barrier();                                             \
    SB;                                                                       \
    v4f S0, GA, GB; v2f P0, P1, P2;                                           \
    DSR(S0, sc_a, (PAR) * 16);                                                \
    DSRB64(P0, pdx_r0, (PAR) * 2048);                                         \
    DSRB64(P1, pdx_r1, (PAR) * 2048);                                         \
    DSRB64(P2, pdx_r2, (PAR) * 2048);                                         \
    float eF, eG;                                                             \
    DSR1(eF, (t + 3) & 31);               /* k_{t+3} -> next e1 */            \
    DSR1(eG, (t + 4) & 31);               /* k_{t+4} -> next e2 */            \
    {                                                                         \
      unsigned _ga = gram_a + (unsigned)(t + 2) * 16u;                        \
      DSR(GA, _ga, 0);                    /* G[t+2] */                        \
      DSR(GB, _ga, 16);                   /* G[t+3] */                        \
    }                                     /* q = 8 */                         \
    WAIT_VM(6);     /* ring slots <= t+11 landed */                           \
    {                                                                         \
      int i0 = t + 16; if (i0 > LM1) i0 = LM1;                                \
      int i1 = t + 17; if (i1 > LM1) i1 = LM1;                                \
      GLL(i0, (t + 16) & 31);                                                 \
      GLL(i1, (t + 17) & 31);                                                 \
    }                                                                         \
    WAIT_LGKM(4);   /* drains S0, P0..P2; leaves [eF,eG,GA,GB] */             \
    float zt = S0.x, z0s = S0.y, z1s = S0.z;                                  \
    bool gt = zt > 0.f;                                                       \
    float zsel = gt ? z1s : z0s;                                              \
    bool gt1 = zsel > 0.f;                                                    \
    float ga = gt ? u : 0.f;              /* g_t * u_t */                     \
    float usel = gt ? u1 : u0;                                                \
    float gb = gt1 ? usel : 0.f;          /* g_{t+1} * u_{t+1} */             \
    {                                                                         \
      v4f gav = {ga, ga, ga, ga};                                             \
      m4[0] = __builtin_elementwise_fma(gav, UA[0], m4[0]);                   \
      m4[1] = __builtin_elementwise_fma(gav, UA[1], m4[1]);                   \
      m4[2] = __builtin_elementwise_fma(gav, UA[2], m4[2]);                   \
      m4[3] = __builtin_elementwise_fma(gav, UA[3], m4[3]);                   \
      v4f gbv = {gb, gb, gb, gb};                                             \
      m4[0] = __builtin_elementwise_fma(gbv, UB[0], m4[0]);                   \
      m4[1] = __builtin_elementwise_fma(gbv, UB[1], m4[1]);                   \
      m4[2] = __builtin_elementwise_fma(gbv, UB[2], m4[2]);                   \
      m4[3] = __builtin_elementwise_fma(gbv, UB[3], m4[3]);                   \
    }                                                                         \
    DSR4(UA, (t + 4) & 31);   /* UA dead -> next pair's NA */                 \
    DSR4(UB, (t + 5) & 31);               /* q = 12 */                        \
    WAIT_LGKM(8);   /* drains eF,eG,GA,GB; leaves [R8] */                     \
    float D1 = (D1own + P0.x) + (P1.x + P2.x);                                \
    float D2 = (D2own + P0.y) + (P1.y + P2.y);                                \
    float vp_n = fmaf(C_nxt, gb, fmaf(X02, ga, D1));  /* vp_{t+2} */          \
    float A_n  = fmaf(X13,  gb, fmaf(X03, ga, D2));   /* M_{t+2} k_{t+3} */   \
    float r2 = 1.0f / (GA.x + EPS);                                           \
    float u_n = fmaf(-r2, vp_n, e2);                  /* u_{t+2} */           \
    s2_cur = GA.x; s2_nxt = GB.x; r_nxt = 1.0f / (GB.x + EPS);                \
    C_cur = GA.y; C_nxt = GB.y;                                               \
    X02 = GA.z; X03 = GA.w; X13 = GB.z;                                       \
    e1 = eF; e2 = eG;                                                         \
    vp = vp_n; u = u_n; A = A_n;                                              \
    t += 2;                                                                   \
  } while (0)

// One block = 4 waves = one batch chain. Lane i owns row i of M; wave w owns
// columns [16w, 16w+16). Phase 1 (parallel): banded Gram table G[t] =
// {s2_t, k_t.k_{t+1}, k_t.k_{t+2}, k_t.k_{t+3}} into LDS. Phase 2: the
// sequential gate recursion with zero per-pair Gram reductions.
__global__ __launch_bounds__(256, 1)
void delta_mem_seq(const float* __restrict__ h,
                   const float* __restrict__ W,
                   const float* __restrict__ bias,
                   float* __restrict__ out,
                   int L) {
  const int tid = threadIdx.x;
  const int w = tid >> 6;
  const int lane = tid & 63;
  __shared__ alignas(16) float kring[32][64];   // 8 KB ring
  __shared__ alignas(16) v4f gram[2048];        // 32 KB banded Gram table
  __shared__ alignas(16) v2f pdx[2][4][64];     // dot partials (parity dbuf)
  __shared__ alignas(16) float scz[2][4];       // z totals (parity dbuf)
  __shared__ alignas(16) float rbuf[64];
  const float* __restrict__ hb = h + (size_t)blockIdx.x * (size_t)L * 64;
  const int LM1 = L - 1;  // gates t = 0..LM1-1

  // ---------- Phase 1: parallel Gram pre-pass (plain C++, pre-ledger) -----
  for (int t0 = tid; t0 <= LM1; t0 += 256) {
    int i1c = (t0 + 1 <= LM1) ? t0 + 1 : LM1;
    int i2c = (t0 + 2 <= LM1) ? t0 + 2 : LM1;
    int i3c = (t0 + 3 <= LM1) ? t0 + 3 : LM1;
    const v4f* r0 = (const v4f*)(hb + (size_t)t0 * 64);
    const v4f* r1 = (const v4f*)(hb + (size_t)i1c * 64);
    const v4f* r2 = (const v4f*)(hb + (size_t)i2c * 64);
    const v4f* r3 = (const v4f*)(hb + (size_t)i3c * 64);
    v4f a0 = v4f{0.f, 0.f, 0.f, 0.f}, a1 = a0, a2 = a0, a3 = a0;
#pragma unroll
    for (int j = 0; j < 16; ++j) {
      v4f a = r0[j];
      a0 = __builtin_elementwise_fma(a, a, a0);
      a1 = __builtin_elementwise_fma(a, r1[j], a1);
      a2 = __builtin_elementwise_fma(a, r2[j], a2);
      a3 = __builtin_elementwise_fma(a, r3[j], a3);
    }
    gram[t0] = (v4f){hsum4(a0), hsum4(a1), hsum4(a2), hsum4(a3)};
  }
  __syncthreads();

  // ---------- Phase 2 setup ------------------------------------------------
  const unsigned kb = (unsigned)(unsigned long long)
      (__attribute__((address_space(3))) const float*)&kring[0][0];
  const unsigned woff = (unsigned)(w << 6);
  const unsigned laneb = (unsigned)(lane << 2);
  const unsigned gram_a = (unsigned)(unsigned long long)
      (__attribute__((address_space(3))) const v4f*)&gram[0];
  const unsigned pb = (unsigned)(unsigned long long)
      (__attribute__((address_space(3))) const v2f*)&pdx[0][0][0];
  const unsigned pdx_w  = pb + (unsigned)(w << 9) + (unsigned)(lane << 3);
  const unsigned pdx_r0 = pb + (unsigned)(((w + 1) & 3) << 9) + (unsigned)(lane << 3);
  const unsigned pdx_r1 = pb + (unsigned)(((w + 2) & 3) << 9) + (unsigned)(lane << 3);
  const unsigned pdx_r2 = pb + (unsigned)(((w + 3) & 3) << 9) + (unsigned)(lane << 3);
  const unsigned sc_a = (unsigned)(unsigned long long)
      (__attribute__((address_space(3))) const float*)&scz[0][0];
  const unsigned sc_pub = sc_a + (unsigned)((w & 3) << 2);

  v4f m4[4];  // M[lane][16w .. 16w+15]
#pragma unroll
  for (int q = 0; q < 4; ++q) m4[q] = v4f{0.f, 0.f, 0.f, 0.f};

  // Ring fill: slots 0..15 (all waves duplicate -> wave-local vmcnt).
#pragma unroll
  for (int i = 0; i < 16; ++i) {
    int idx = (i <= LM1) ? i : LM1;
    GLL(idx, i);
  }
  WAIT_VM(0);

  // Pre-ledger C++ LDS reads: own-row elements + initial Gram actives.
  float e0 = kring[0][lane];
  float e1 = kring[1][lane], e2 = kring[2][lane];
  v4f G0 = gram[0], G1 = gram[1];
  float s2_cur = G0.x, s2_nxt = G1.x;
  float C_cur = G0.y, C_nxt = G1.y;
  float X02 = G0.z, X03 = G0.w, X13 = G1.z;
  float r_nxt = 1.0f / (G1.x + EPS);
  float vp = 0.f;  // vp_0 = M_0 k_0 = 0
  float u = e0;    // u_0 = k_0
  float A = 0.f;   // M_0 k_1 = 0
  int t = 0;
  WAIT_LGKM(0);    // anchor: C++ reads drained; counted ledger starts clean

  // Register banks: U = slots 0,1 (first update), drained; N = slots 2,3
  // left IN FLIGHT -> loop-entry queue = [R8].
  v4f U0[4], U1[4], N0[4], N1[4];
  DSR4(U0, 0); DSR4(U1, 1);
  WAIT_LGKM(0);
  DSR4(N0, 2); DSR4(N1, 3);
  SB;

  while (t + 3 < LM1) {   // 2x unrolled bank-role rotation; PAR alternates
    PAIR(U0, U1, N0, N1, 0);
    PAIR(N0, N1, U0, U1, 1);
    WAIT_LGKM(0);  // backedge drain: no in-flight asm dsts cross the branch
    SB;
  }
  if (t + 1 < LM1) {
    PAIR(U0, U1, N0, N1, 0);
    WAIT_LGKM(0);
    SB;
  }

  // Drain ALL in-flight DMAs; keep dsts formally live (R5-R7 lesson).
  asm volatile("s_waitcnt vmcnt(0) lgkmcnt(0)" ::: "memory");
  SB;
  KEEP4(U0); KEEP4(U1); KEEP4(N0); KEEP4(N1);

  if (t < LM1) {  // odd leftover gate (replicated in all waves)
    float wz = u * fmaf(s2_cur, u, 2.0f * vp);
    WAVE_RED1(wz);
    float zt = rl63(wz);
    float coef = (zt > 0.f) ? C_cur : 0.f;
    vp = fmaf(coef, u, A);  // read = M_L k_{L-1}
  }

  if (w == 0) rbuf[lane] = vp;
  __syncthreads();

  if (w == 0) {
    const v4f* wv = (const v4f*)(W + lane * 64);
    const v4f* rv = (const v4f*)rbuf;
    v4f acc = v4f{0.f, 0.f, 0.f, 0.f};
#pragma unroll
    for (int q = 0; q < 16; ++q)
      acc = __builtin_elementwise_fma(wv[q], rv[q], acc);
    out[(size_t)blockIdx.x * 64 + lane] = bias[lane] + hsum4(acc);
  }
}

extern "C" void kernel_launch(void* const* d_in, const int* in_sizes, int n_in,
                              void* d_out, int out_size, void* d_ws, size_t ws_size,
                              hipStream_t stream) {
  const float* h    = (const float*)d_in[0];
  const float* W    = (const float*)d_in[1];
  const float* bias = (const float*)d_in[2];
  float* out = (float*)d_out;

  const int H = in_sizes[2];            // 64
  const int B = out_size / H;           // 256
  const int L = in_sizes[0] / (B * H);  // 2048

  delta_mem_seq<<<B, 256, 0, stream>>>(h, W, bias, out, L);
}

// Round 18
// 576.504 us; speedup vs baseline: 1.5399x; 1.2392x over previous
//
#include <hip/hip_runtime.h>

typedef float v4f __attribute__((ext_vector_type(4)));
static constexpr float EPS = 1e-6f;

#define DPP_ADD(x, ctrl, rmask)                                               \
  x += __builtin_bit_cast(float, __builtin_amdgcn_update_dpp(                 \
           0, __builtin_bit_cast(int, x), ctrl, rmask, 0xf, true))

#define WAVE_RED1(a)                                                          \
  do {                                                                        \
    DPP_ADD(a, 0x111, 0xf); DPP_ADD(a, 0x112, 0xf); DPP_ADD(a, 0x114, 0xf);  \
    DPP_ADD(a, 0x118, 0xf); DPP_ADD(a, 0x142, 0xa); DPP_ADD(a, 0x143, 0xc);  \
  } while (0)

__device__ __forceinline__ float rl63(float x) {
  return __builtin_bit_cast(
      float, __builtin_amdgcn_readlane(__builtin_bit_cast(int, x), 63));
}
__device__ __forceinline__ float hsum4(v4f v) {
  return (v.x + v.y) + (v.z + v.w);
}

// Async global->LDS DMA (no register writeback -> regalloc-sound).
#define GLL(idx, slot)                                                        \
  __builtin_amdgcn_global_load_lds(                                           \
      (const __attribute__((address_space(1))) void*)(hb + (size_t)(idx) * 64 + lane), \
      (__attribute__((address_space(3))) void*)&kring[(slot)][0], 4, 0, 0)

#define DSR(dst, a, offb)                                                     \
  asm volatile("ds_read_b128 %0, %1 offset:%2"                                \
               : "=&v"(dst) : "v"(a), "i"(offb))
#define DSR1O(dst, a, offb)                                                   \
  asm volatile("ds_read_b32 %0, %1 offset:%2"                                 \
               : "=&v"(dst) : "v"(a), "i"(offb))
#define DSW32O(a, d, offb)                                                    \
  asm volatile("ds_write_b32 %0, %1 offset:%2"                                \
               :: "v"(a), "v"(d), "i"(offb) : "memory")

// 4 reads = this wave's 16-col slice of one k vector -> register bank.
#define DSR4(B, slot)                                                         \
  do {                                                                        \
    unsigned _a = kb + (unsigned)(slot) * 256u + woff;                        \
    DSR(B[0], _a, 0); DSR(B[1], _a, 16); DSR(B[2], _a, 32); DSR(B[3], _a, 48);\
  } while (0)

#define SB __builtin_amdgcn_sched_barrier(0)
#define WAIT_LGKM(n)                                                          \
  do { asm volatile("s_waitcnt lgkmcnt(" #n ")" ::: "memory"); SB; } while (0)
#define WAIT_VM(n)                                                            \
  do { asm volatile("s_waitcnt vmcnt(" #n ")" ::: "memory"); SB; } while (0)
#define KEEP4(BK)                                                             \
  asm volatile("" :: "v"(BK[0]), "v"(BK[1]), "v"(BK[2]), "v"(BK[3]))

// Packed triangular Gram index: diag t -> t; pair (s<t) -> 8 + s(15-s)/2 + (t-s-1)
#define GOFF(s, t) (8 + ((s) * (15 - (s))) / 2 + ((t) - (s)-1))
#define GS(s, t) Gp[GOFF(s, t) >> 2][GOFF(s, t) & 3]

// One gate step: vp from basis scalars (registers only), z via ONE DPP
// reduction. No LDS, no barrier. All waves replicate -> identical gates.
#define STEPX(t, SUM)                                                         \
  do {                                                                        \
    float vp_ = (SUM);                                                        \
    float u_ = fmaf(-r[t], vp_, e[t]);                                        \
    float z_ = u_ * fmaf(s2[t], u_, 2.0f * vp_);                              \
    WAVE_RED1(z_);                                                            \
    float zt_ = rl63(z_);                                                     \
    wu[t] = (zt_ > 0.f) ? u_ : 0.f;                                           \
  } while (0)

// M-update consume: M[lane][cols] += wu[t] * k_t[cols]
#define MCON(SET, t)                                                          \
  do {                                                                        \
    v4f wv_ = {wu[t], wu[t], wu[t], wu[t]};                                   \
    m4[0] = __builtin_elementwise_fma(wv_, SET[0], m4[0]);                    \
    m4[1] = __builtin_elementwise_fma(wv_, SET[1], m4[1]);                    \
    m4[2] = __builtin_elementwise_fma(wv_, SET[2], m4[2]);                    \
    m4[3] = __builtin_elementwise_fma(wv_, SET[3], m4[3]);                    \
  } while (0)
// P-dot consume: pd[j] = (own 16-col slice of M) . k_j
#define PCON(SET, j)                                                          \
  do {                                                                        \
    v4f a_ = m4[0] * SET[0];                                                  \
    a_ = __builtin_elementwise_fma(m4[1], SET[1], a_);                        \
    a_ = __builtin_elementwise_fma(m4[2], SET[2], a_);                        \
    a_ = __builtin_elementwise_fma(m4[3], SET[3], a_);                        \
    pd[j] = hsum4(a_);                                                        \
  } while (0)

// Chunked-basis delta rule. One block = 4 waves = one batch chain.
// Lane i owns row i of M; wave w owns columns [16w,16w+16).
// Phase 1 (parallel): packed within-chunk Gram tables (static) -> LDS.
// Phase 2: per chunk of 8 gates: CORE = 8 x {register FMAs + 1 DPP-reduce}
// (no LDS/barrier per step); BOUNDARY = pipelined 16-bank LDS pass
// (8 rank-1 M updates + 8 col-split dots b_j = M k_j) + ONE barrier.
__global__ __launch_bounds__(256, 1)
void delta_mem_seq(const float* __restrict__ h,
                   const float* __restrict__ W,
                   const float* __restrict__ bias,
                   float* __restrict__ out,
                   int L) {
  const int tid = threadIdx.x;
  const int w = tid >> 6;
  const int lane = tid & 63;
  __shared__ float gramL[256 * 40];             // 40 KB packed Gram
  __shared__ alignas(16) float kring[32][64];   // 8 KB ring
  __shared__ float pdx[2][4][8][64];            // 16 KB exchange (SoA)
  __shared__ alignas(16) float rbuf[64];
  const float* __restrict__ hb = h + (size_t)blockIdx.x * (size_t)L * 64;
  const int LM1 = L - 1;      // gates t = 0..LM1-1
  const int NCF = LM1 >> 3;   // full chunks (255 for L=2048)
  const int tail = LM1 & 7;   // leftover gates (7)

  // ---------------- Phase 1: packed Gram per chunk (thread = chunk) -------
  {
    int c1 = tid;  // 256 threads = up to 256 chunks
    if (c1 * 8 <= LM1) {
      for (int s = 0; s < 8; ++s) {
        int ra = 8 * c1 + s; if (ra > L - 1) ra = L - 1;
        const v4f* prs = (const v4f*)(hb + (size_t)ra * 64);
        v4f rowS[16];
#pragma unroll
        for (int q = 0; q < 16; ++q) rowS[q] = prs[q];
        for (int t = s; t < 8; ++t) {
          int rb = 8 * c1 + t; if (rb > L - 1) rb = L - 1;
          const v4f* prt = (const v4f*)(hb + (size_t)rb * 64);
          v4f acc = v4f{0.f, 0.f, 0.f, 0.f};
#pragma unroll
          for (int q = 0; q < 16; ++q)
            acc = __builtin_elementwise_fma(rowS[q], prt[q], acc);
          float d = hsum4(acc);
          int idx = (s == t) ? s : (8 + (s * (15 - s)) / 2 + (t - s - 1));
          gramL[c1 * 40 + idx] = d;
        }
      }
    }
  }
  __syncthreads();  // gram visible; vm/lgkm fully drained (clean ledger)

  // ---------------- Phase 2 setup ------------------------------------------
  const unsigned kb = (unsigned)(unsigned long long)
      (__attribute__((address_space(3))) const float*)&kring[0][0];
  const unsigned woff = (unsigned)(w << 6);
  const unsigned laneb = (unsigned)(lane << 2);
  const unsigned gramA = (unsigned)(unsigned long long)
      (__attribute__((address_space(3))) const float*)&gramL[0];
  const unsigned pdxA = (unsigned)(unsigned long long)
      (__attribute__((address_space(3))) const float*)&pdx[0][0][0][0];

  v4f m4[4];
#pragma unroll
  for (int q = 0; q < 4; ++q) m4[q] = v4f{0.f, 0.f, 0.f, 0.f};

  // Prologue: ring slots 0..15 (all waves duplicate -> wave-local vmcnt).
#pragma unroll
  for (int i = 0; i < 16; ++i) {
    int idx = (i <= LM1) ? i : LM1;
    GLL(idx, i);
  }
  WAIT_VM(8);  // slots 0..7 landed; 8 outstanding (slots 8..15) = steady state

  v4f Gp[10];
  float e[8], b[8], wu[8], r[8], s2[8], pd[8];
  {  // Gp(chunk 0) + e(0..7); b = 0 (M_0 = 0)
    unsigned ga = gramA;
    DSR(Gp[0], ga, 0);   DSR(Gp[1], ga, 16);  DSR(Gp[2], ga, 32);
    DSR(Gp[3], ga, 48);  DSR(Gp[4], ga, 64);  DSR(Gp[5], ga, 80);
    DSR(Gp[6], ga, 96);  DSR(Gp[7], ga, 112); DSR(Gp[8], ga, 128);
    DSR(Gp[9], ga, 144);
    unsigned eb = kb + laneb;
    DSR1O(e[0], eb, 0);    DSR1O(e[1], eb, 256);  DSR1O(e[2], eb, 512);
    DSR1O(e[3], eb, 768);  DSR1O(e[4], eb, 1024); DSR1O(e[5], eb, 1280);
    DSR1O(e[6], eb, 1536); DSR1O(e[7], eb, 1792);
    WAIT_LGKM(0);
#pragma unroll
    for (int t = 0; t < 8; ++t) {
      s2[t] = Gp[t >> 2][t & 3];
      r[t] = 1.0f / (s2[t] + EPS);
      b[t] = 0.f;
    }
  }

  v4f B0[4], B1[4], B2[4];
  int T0 = 0;
  for (int c = 0; c < NCF; ++c, T0 += 8) {
    // ---------------- CORE: 8 gates, registers + 1 DPP-reduce each --------
    STEPX(0, b[0]);
    STEPX(1, fmaf(GS(0, 1), wu[0], b[1]));
    STEPX(2, b[2] + (GS(0, 2) * wu[0] + GS(1, 2) * wu[1]));
    STEPX(3, b[3] + ((GS(0, 3) * wu[0] + GS(1, 3) * wu[1]) + GS(2, 3) * wu[2]));
    STEPX(4, b[4] + ((GS(0, 4) * wu[0] + GS(1, 4) * wu[1]) +
                     (GS(2, 4) * wu[2] + GS(3, 4) * wu[3])));
    STEPX(5, b[5] + (((GS(0, 5) * wu[0] + GS(1, 5) * wu[1]) +
                      (GS(2, 5) * wu[2] + GS(3, 5) * wu[3])) +
                     GS(4, 5) * wu[4]));
    STEPX(6, b[6] + (((GS(0, 6) * wu[0] + GS(1, 6) * wu[1]) +
                      (GS(2, 6) * wu[2] + GS(3, 6) * wu[3])) +
                     (GS(4, 6) * wu[4] + GS(5, 6) * wu[5])));
    STEPX(7, b[7] + (((GS(0, 7) * wu[0] + GS(1, 7) * wu[1]) +
                      (GS(2, 7) * wu[2] + GS(3, 7) * wu[3])) +
                     ((GS(4, 7) * wu[4] + GS(5, 7) * wu[5]) +
                      GS(6, 7) * wu[6])));

    // ---------------- BOUNDARY --------------------------------------------
    int par = c & 1;
    // prefetch: issue next ring batch (idx T0+16..23; slots wrap mod 32)
#pragma unroll
    for (int i = 0; i < 8; ++i) {
      int gidx = T0 + 16 + i; if (gidx > LM1 + 1) gidx = LM1 + 1;
      if (gidx > L - 1) gidx = L - 1;
      GLL(gidx, (T0 + 16 + i) & 31);
    }
    // 16-bank pipeline, 3 deep: banks 0..7 = M update (k_t), 8..15 = P dots.
    DSR4(B0, (T0 + 0) & 31); DSR4(B1, (T0 + 1) & 31); DSR4(B2, (T0 + 2) & 31);
    WAIT_LGKM(8); MCON(B0, 0); DSR4(B0, (T0 + 3) & 31);
    WAIT_LGKM(8); MCON(B1, 1); DSR4(B1, (T0 + 4) & 31);
    WAIT_LGKM(8); MCON(B2, 2); DSR4(B2, (T0 + 5) & 31);
    WAIT_LGKM(8); MCON(B0, 3); DSR4(B0, (T0 + 6) & 31);
    WAIT_LGKM(8); MCON(B1, 4); DSR4(B1, (T0 + 7) & 31);
    WAIT_LGKM(8); MCON(B2, 5); WAIT_VM(8); DSR4(B2, (T0 + 8) & 31);
    WAIT_LGKM(8); MCON(B0, 6); DSR4(B0, (T0 + 9) & 31);
    WAIT_LGKM(8); MCON(B1, 7); DSR4(B1, (T0 + 10) & 31);
    WAIT_LGKM(8); PCON(B2, 0); DSR4(B2, (T0 + 11) & 31);
    WAIT_LGKM(8); PCON(B0, 1); DSR4(B0, (T0 + 12) & 31);
    WAIT_LGKM(8); PCON(B1, 2); DSR4(B1, (T0 + 13) & 31);
    WAIT_LGKM(8); PCON(B2, 3); DSR4(B2, (T0 + 14) & 31);
    WAIT_LGKM(8); PCON(B0, 4); DSR4(B0, (T0 + 15) & 31);
    WAIT_LGKM(8); PCON(B1, 5);
    WAIT_LGKM(4); PCON(B2, 6);
    WAIT_LGKM(0); PCON(B0, 7);

    // publish partials (SoA, conflict-free), one barrier per chunk
    {
      unsigned pwr = pdxA + (unsigned)(par << 13) + (unsigned)(w << 11) + laneb;
      DSW32O(pwr, pd[0], 0);    DSW32O(pwr, pd[1], 256);
      DSW32O(pwr, pd[2], 512);  DSW32O(pwr, pd[3], 768);
      DSW32O(pwr, pd[4], 1024); DSW32O(pwr, pd[5], 1280);
      DSW32O(pwr, pd[6], 1536); DSW32O(pwr, pd[7], 1792);
    }
    WAIT_LGKM(0);
    __builtin_amdgcn_s_barrier();
    SB;

    // gather: partials (canonical order), Gp(c+1), e(c+1)
    float P0[8], P1[8], P2[8], P3[8];
    {
      unsigned prd = pdxA + (unsigned)(par << 13) + laneb;
      DSR1O(P0[0], prd, 0);    DSR1O(P0[1], prd, 256);
      DSR1O(P0[2], prd, 512);  DSR1O(P0[3], prd, 768);
      DSR1O(P0[4], prd, 1024); DSR1O(P0[5], prd, 1280);
      DSR1O(P0[6], prd, 1536); DSR1O(P0[7], prd, 1792);
      DSR1O(P1[0], prd, 2048); DSR1O(P1[1], prd, 2304);
      DSR1O(P1[2], prd, 2560); DSR1O(P1[3], prd, 2816);
      DSR1O(P1[4], prd, 3072); DSR1O(P1[5], prd, 3328);
      DSR1O(P1[6], prd, 3584); DSR1O(P1[7], prd, 3840);
      DSR1O(P2[0], prd, 4096); DSR1O(P2[1], prd, 4352);
      DSR1O(P2[2], prd, 4608); DSR1O(P2[3], prd, 4864);
      DSR1O(P2[4], prd, 5120); DSR1O(P2[5], prd, 5376);
      DSR1O(P2[6], prd, 5632); DSR1O(P2[7], prd, 5888);
      DSR1O(P3[0], prd, 6144); DSR1O(P3[1], prd, 6400);
      DSR1O(P3[2], prd, 6656); DSR1O(P3[3], prd, 6912);
      DSR1O(P3[4], prd, 7168); DSR1O(P3[5], prd, 7424);
      DSR1O(P3[6], prd, 7680); DSR1O(P3[7], prd, 7936);
      unsigned ga = gramA + (unsigned)(T0 * 20 + 160);  // chunk c+1
      DSR(Gp[0], ga, 0);   DSR(Gp[1], ga, 16);  DSR(Gp[2], ga, 32);
      DSR(Gp[3], ga, 48);  DSR(Gp[4], ga, 64);  DSR(Gp[5], ga, 80);
      DSR(Gp[6], ga, 96);  DSR(Gp[7], ga, 112); DSR(Gp[8], ga, 128);
      DSR(Gp[9], ga, 144);
      unsigned eb = kb + (unsigned)(((T0 + 8) & 31) * 256) + laneb;  // no wrap
      DSR1O(e[0], eb, 0);    DSR1O(e[1], eb, 256);  DSR1O(e[2], eb, 512);
      DSR1O(e[3], eb, 768);  DSR1O(e[4], eb, 1024); DSR1O(e[5], eb, 1280);
      DSR1O(e[6], eb, 1536); DSR1O(e[7], eb, 1792);
    }
    WAIT_LGKM(0);
#pragma unroll
    for (int j = 0; j < 8; ++j)  // canonical order -> identical in all waves
      b[j] = (P0[j] + P1[j]) + (P2[j] + P3[j]);
#pragma unroll
    for (int t = 0; t < 8; ++t) {
      s2[t] = Gp[t >> 2][t & 3];
      r[t] = 1.0f / (s2[t] + EPS);
    }
  }

  // ---------------- TAIL: `tail` gates + final read -------------------------
  if (tail > 0) STEPX(0, b[0]);
  if (tail > 1) STEPX(1, fmaf(GS(0, 1), wu[0], b[1]));
  if (tail > 2) STEPX(2, b[2] + (GS(0, 2) * wu[0] + GS(1, 2) * wu[1]));
  if (tail > 3) STEPX(3, b[3] + ((GS(0, 3) * wu[0] + GS(1, 3) * wu[1]) +
                                 GS(2, 3) * wu[2]));
  if (tail > 4) STEPX(4, b[4] + ((GS(0, 4) * wu[0] + GS(1, 4) * wu[1]) +
                                 (GS(2, 4) * wu[2] + GS(3, 4) * wu[3])));
  if (tail > 5) STEPX(5, b[5] + (((GS(0, 5) * wu[0] + GS(1, 5) * wu[1]) +
                                  (GS(2, 5) * wu[2] + GS(3, 5) * wu[3])) +
                                 GS(4, 5) * wu[4]));
  if (tail > 6) STEPX(6, b[6] + (((GS(0, 6) * wu[0] + GS(1, 6) * wu[1]) +
                                  (GS(2, 6) * wu[2] + GS(3, 6) * wu[3])) +
                                 (GS(4, 6) * wu[4] + GS(5, 6) * wu[5])));

  WAIT_VM(0);  // drain remaining DMAs (all tail banks landed long ago)
  float fd = 0.f;
  // 8-bank pipeline: i<tail -> M update; i==tail -> final dot (k_{L-1});
  // bank idx T0+i: T0+tail == L-1 exactly.
#define TSTEP(SET, i, WN)                                                     \
  do {                                                                        \
    WAIT_LGKM(WN);                                                            \
    if ((i) < tail) { MCON(SET, i); }                                         \
    else if ((i) == tail) { PCON(SET, 0); fd = pd[0]; }                       \
  } while (0)
  DSR4(B0, (T0 + 0) & 31); DSR4(B1, (T0 + 1) & 31); DSR4(B2, (T0 + 2) & 31);
  TSTEP(B0, 0, 8); DSR4(B0, (T0 + 3) & 31);
  TSTEP(B1, 1, 8); DSR4(B1, (T0 + 4) & 31);
  TSTEP(B2, 2, 8); DSR4(B2, (T0 + 5) & 31);
  TSTEP(B0, 3, 8); DSR4(B0, (T0 + 6) & 31);
  TSTEP(B1, 4, 8); DSR4(B1, (T0 + 7) & 31);
  TSTEP(B2, 5, 8);
  TSTEP(B0, 6, 4);
  TSTEP(B1, 7, 0);

  // exchange final-read partials (parity region distinct from last boundary)
  {
    int parT = NCF & 1;
    unsigned fwr = pdxA + (unsigned)(parT << 13) + (unsigned)(w << 11) + laneb;
    DSW32O(fwr, fd, 0);
  }
  WAIT_LGKM(0);
  __builtin_amdgcn_s_barrier();
  SB;
  {
    int parT = NCF & 1;
    unsigned frd = pdxA + (unsigned)(parT << 13) + laneb;
    float f0, f1, f2, f3;
    DSR1O(f0, frd, 0); DSR1O(f1, frd, 2048);
    DSR1O(f2, frd, 4096); DSR1O(f3, frd, 6144);
    WAIT_LGKM(0);
    float rd = (f0 + f1) + (f2 + f3);  // read[lane] = (M_final k_{L-1})[lane]
    if (w == 0) rbuf[lane] = rd;
  }
  asm volatile("s_waitcnt vmcnt(0) lgkmcnt(0)" ::: "memory");
  SB;
  KEEP4(B0); KEEP4(B1); KEEP4(B2);
  __syncthreads();

  if (w == 0) {
    const v4f* wv = (const v4f*)(W + lane * 64);
    const v4f* rv = (const v4f*)rbuf;
    v4f acc = v4f{0.f, 0.f, 0.f, 0.f};
#pragma unroll
    for (int q = 0; q < 16; ++q)
      acc = __builtin_elementwise_fma(wv[q], rv[q], acc);
    out[(size_t)blockIdx.x * 64 + lane] = bias[lane] + hsum4(acc);
  }
}

extern "C" void kernel_launch(void* const* d_in, const int* in_sizes, int n_in,
                              void* d_out, int out_size, void* d_ws, size_t ws_size,
                              hipStream_t stream) {
  const float* h    = (const float*)d_in[0];
  const float* W    = (const float*)d_in[1];
  const float* bias = (const float*)d_in[2];
  float* out = (float*)d_out;

  const int H = in_sizes[2];            // 64
  const int B = out_size / H;           // 256
  const int L = in_sizes[0] / (B * H);  // 2048

  delta_mem_seq<<<B, 256, 0, stream>>>(h, W, bias, out, L);
}